// Round 1
// baseline (6552.655 us; speedup 1.0000x reference)
//
#include <hip/hip_runtime.h>

#define N_NODES 100000
#define N_EDGES 1600000
#define N_GRAPHS 2048
#define NFEAT 78
#define DIM 32
#define NLAYERS 5
#define OUTD 128
#define BN_EPS 1e-5f

// ---------------- GEMM1: y = h @ W1 ; s = y + b1 ----------------
template<int K>
__global__ __launch_bounds__(256) void gemm1_kernel(
    const float* __restrict__ h, const float* __restrict__ W,
    const float* __restrict__ b, float* __restrict__ y,
    float* __restrict__ s, int n)
{
    __shared__ float Wl[K * DIM];
    __shared__ float bl[DIM];
    for (int i = threadIdx.x; i < K * DIM; i += 256) Wl[i] = W[i];
    if (threadIdx.x < DIM) bl[threadIdx.x] = b[threadIdx.x];
    __syncthreads();

    int row = blockIdx.x * 256 + threadIdx.x;
    if (row >= n) return;

    float acc[DIM];
#pragma unroll
    for (int j = 0; j < DIM; ++j) acc[j] = 0.f;

    const float* hr = h + (long)row * K;
    for (int k = 0; k < K; ++k) {
        float xv = hr[k];
#pragma unroll
        for (int j = 0; j < DIM; ++j) acc[j] += xv * Wl[k * DIM + j];
    }

    float4* yv = (float4*)(y + (long)row * DIM);
    float4* sv = (float4*)(s + (long)row * DIM);
#pragma unroll
    for (int q = 0; q < DIM / 4; ++q) {
        float4 a = make_float4(acc[q*4+0], acc[q*4+1], acc[q*4+2], acc[q*4+3]);
        yv[q] = a;
        float4 sb = make_float4(a.x + bl[q*4+0], a.y + bl[q*4+1],
                                a.z + bl[q*4+2], a.w + bl[q*4+3]);
        sv[q] = sb;
    }
}

// ---------------- scatter: s[dst] += y[src] over edges ----------------
__global__ __launch_bounds__(256) void scatter_kernel(
    const int* __restrict__ ei, const float* __restrict__ y, float* __restrict__ s)
{
    int t = blockIdx.x * 256 + threadIdx.x;
    if (t >= N_EDGES * 8) return;
    int e = t >> 3;
    int p = t & 7;
    int src = ei[e];
    int dst = ei[N_EDGES + e];
    float4 v = *(const float4*)(y + (long)src * DIM + p * 4);
    float* d = s + (long)dst * DIM + p * 4;
    atomicAdd(d + 0, v.x);
    atomicAdd(d + 1, v.y);
    atomicAdd(d + 2, v.z);
    atomicAdd(d + 3, v.w);
}

// ------- GEMM2: z = relu(relu(s) @ W2 + b2); accumulate BN stats -------
__global__ __launch_bounds__(256) void gemm2_kernel(
    const float* __restrict__ s, const float* __restrict__ W2,
    const float* __restrict__ b2, float* __restrict__ z,
    float* __restrict__ stats, int n)
{
    __shared__ float Wl[DIM * DIM];
    __shared__ float bl[DIM];
    for (int i = threadIdx.x; i < DIM * DIM; i += 256) Wl[i] = W2[i];
    if (threadIdx.x < DIM) bl[threadIdx.x] = b2[threadIdx.x];
    __syncthreads();

    int row = blockIdx.x * 256 + threadIdx.x;
    float zv[DIM];
    if (row < n) {
        float a[DIM];
        const float4* sv = (const float4*)(s + (long)row * DIM);
#pragma unroll
        for (int q = 0; q < DIM / 4; ++q) {
            float4 v = sv[q];
            a[q*4+0] = fmaxf(v.x, 0.f);
            a[q*4+1] = fmaxf(v.y, 0.f);
            a[q*4+2] = fmaxf(v.z, 0.f);
            a[q*4+3] = fmaxf(v.w, 0.f);
        }
#pragma unroll
        for (int j = 0; j < DIM; ++j) zv[j] = bl[j];
#pragma unroll
        for (int k = 0; k < DIM; ++k) {
#pragma unroll
            for (int j = 0; j < DIM; ++j) zv[j] += a[k] * Wl[k * DIM + j];
        }
#pragma unroll
        for (int j = 0; j < DIM; ++j) zv[j] = fmaxf(zv[j], 0.f);
        float4* zp = (float4*)(z + (long)row * DIM);
#pragma unroll
        for (int q = 0; q < DIM / 4; ++q)
            zp[q] = make_float4(zv[q*4+0], zv[q*4+1], zv[q*4+2], zv[q*4+3]);
    } else {
#pragma unroll
        for (int j = 0; j < DIM; ++j) zv[j] = 0.f;
    }

    // per-wave butterfly reduce of sum and sumsq across 64 lanes
    float sq[DIM];
#pragma unroll
    for (int j = 0; j < DIM; ++j) sq[j] = zv[j] * zv[j];
#pragma unroll
    for (int off = 1; off < 64; off <<= 1) {
#pragma unroll
        for (int j = 0; j < DIM; ++j) {
            zv[j] += __shfl_xor(zv[j], off, 64);
            sq[j] += __shfl_xor(sq[j], off, 64);
        }
    }
    if ((threadIdx.x & 63) == 0) {
#pragma unroll
        for (int j = 0; j < DIM; ++j) {
            atomicAdd(&stats[j], zv[j]);
            atomicAdd(&stats[DIM + j], sq[j]);
        }
    }
}

// ---------------- BN apply (in place on z) ----------------
__global__ __launch_bounds__(256) void bn_kernel(
    float* __restrict__ z, const float* __restrict__ stats,
    const float* __restrict__ gamma, const float* __restrict__ beta)
{
    __shared__ float sc[DIM], sh[DIM];
    if (threadIdx.x < DIM) {
        int c = threadIdx.x;
        const float invN = 1.0f / (float)N_NODES;
        float mu = stats[c] * invN;
        float var = stats[DIM + c] * invN - mu * mu;
        float scale = gamma[c] * rsqrtf(var + BN_EPS);
        sc[c] = scale;
        sh[c] = beta[c] - mu * scale;
    }
    __syncthreads();
    int t = blockIdx.x * 256 + threadIdx.x;   // float4 index
    if (t >= N_NODES * (DIM / 4)) return;
    float4 v = ((float4*)z)[t];
    int c = (t & 7) * 4;
    v.x = v.x * sc[c + 0] + sh[c + 0];
    v.y = v.y * sc[c + 1] + sh[c + 1];
    v.z = v.z * sc[c + 2] + sh[c + 2];
    v.w = v.w * sc[c + 3] + sh[c + 3];
    ((float4*)z)[t] = v;
}

// ---------------- global add pool ----------------
__global__ __launch_bounds__(256) void pool_kernel(
    const float* __restrict__ z, const int* __restrict__ batch,
    float* __restrict__ pooled)
{
    int t = blockIdx.x * 256 + threadIdx.x;
    if (t >= N_NODES * 8) return;
    int nrow = t >> 3;
    int p = t & 7;
    int g = batch[nrow];
    float4 v = *(const float4*)(z + (long)nrow * DIM + p * 4);
    float* d = pooled + (long)g * DIM + p * 4;
    atomicAdd(d + 0, v.x);
    atomicAdd(d + 1, v.y);
    atomicAdd(d + 2, v.z);
    atomicAdd(d + 3, v.w);
}

// ---------------- final FC + ReLU ----------------
__global__ __launch_bounds__(256) void fc_kernel(
    const float* __restrict__ pooled, const float* __restrict__ Wfc,
    const float* __restrict__ bfc, float* __restrict__ out)
{
    __shared__ float Wl[DIM * OUTD];   // 16 KB
    for (int i = threadIdx.x; i < DIM * OUTD; i += 256) Wl[i] = Wfc[i];
    __syncthreads();
    int t = blockIdx.x * 256 + threadIdx.x;
    if (t >= N_GRAPHS * OUTD) return;
    int g = t >> 7;       // /128
    int o = t & (OUTD - 1);
    float acc = bfc[o];
    const float* pr = pooled + (long)g * DIM;
#pragma unroll
    for (int k = 0; k < DIM; ++k) acc += pr[k] * Wl[k * OUTD + o];
    out[t] = fmaxf(acc, 0.f);
}

extern "C" void kernel_launch(void* const* d_in, const int* in_sizes, int n_in,
                              void* d_out, int out_size, void* d_ws, size_t ws_size,
                              hipStream_t stream) {
    const float* x      = (const float*)d_in[0];
    const int*   ei     = (const int*)  d_in[1];
    const int*   batch  = (const int*)  d_in[2];
    const float* W1_0   = (const float*)d_in[3];
    const float* W1_rest= (const float*)d_in[4];
    const float* b1     = (const float*)d_in[5];
    const float* W2     = (const float*)d_in[6];
    const float* b2     = (const float*)d_in[7];
    const float* gamma  = (const float*)d_in[8];
    const float* beta   = (const float*)d_in[9];
    const float* Wfc    = (const float*)d_in[10];
    const float* bfc    = (const float*)d_in[11];
    float* out = (float*)d_out;

    char* ws = (char*)d_ws;
    const size_t nb = (size_t)N_NODES * DIM * sizeof(float);   // 12.8 MB
    float* y      = (float*)(ws);
    float* s      = (float*)(ws + nb);
    float* z      = (float*)(ws + 2 * nb);
    float* pooled = (float*)(ws + 3 * nb);
    float* stats  = pooled + (size_t)N_GRAPHS * DIM;           // 5*64 floats

    // zero pooled + all per-layer stats (contiguous) every launch
    hipMemsetAsync(pooled, 0,
                   ((size_t)N_GRAPHS * DIM + NLAYERS * 2 * DIM) * sizeof(float),
                   stream);

    const int rowBlocks = (N_NODES + 255) / 256;
    const int elemBlocks = (N_NODES * 8 + 255) / 256;

    const float* hin = x;
    for (int i = 0; i < NLAYERS; ++i) {
        if (i == 0) {
            gemm1_kernel<NFEAT><<<rowBlocks, 256, 0, stream>>>(
                hin, W1_0, b1, y, s, N_NODES);
        } else {
            gemm1_kernel<DIM><<<rowBlocks, 256, 0, stream>>>(
                hin, W1_rest + (size_t)(i - 1) * DIM * DIM, b1 + i * DIM,
                y, s, N_NODES);
        }
        scatter_kernel<<<(N_EDGES * 8) / 256, 256, 0, stream>>>(ei, y, s);
        gemm2_kernel<<<rowBlocks, 256, 0, stream>>>(
            s, W2 + (size_t)i * DIM * DIM, b2 + i * DIM, z,
            stats + i * 2 * DIM, N_NODES);
        bn_kernel<<<elemBlocks, 256, 0, stream>>>(
            z, stats + i * 2 * DIM, gamma + i * DIM, beta + i * DIM);
        hin = z;
    }

    pool_kernel<<<elemBlocks, 256, 0, stream>>>(z, batch, pooled);
    fc_kernel<<<(N_GRAPHS * OUTD) / 256, 256, 0, stream>>>(pooled, Wfc, bfc, out);
}

// Round 2
// 811.090 us; speedup vs baseline: 8.0788x; 8.0788x over previous
//
#include <hip/hip_runtime.h>

#define N_NODES 100000
#define N_EDGES 1600000
#define N_GRAPHS 2048
#define NFEAT 78
#define DIM 32
#define NLAYERS 5
#define OUTD 128
#define BN_EPS 1e-5f
#define SCAN_BLK 1024   // elements per scan block (256 thr * 4)

// ---------------- CSR build ----------------
__global__ __launch_bounds__(256) void deg_kernel(
    const int* __restrict__ ei, int* __restrict__ counts)
{
    int e = blockIdx.x * 256 + threadIdx.x;
    if (e >= N_EDGES) return;
    atomicAdd(&counts[ei[N_EDGES + e]], 1);
}

__global__ __launch_bounds__(256) void scan_a_kernel(
    const int* __restrict__ counts, int* __restrict__ blockSums)
{
    __shared__ int sd[256];
    int tid = threadIdx.x;
    int base = blockIdx.x * SCAN_BLK + tid * 4;
    int s = 0;
#pragma unroll
    for (int k = 0; k < 4; ++k) {
        int i = base + k;
        if (i < N_NODES) s += counts[i];
    }
    sd[tid] = s; __syncthreads();
    for (int off = 128; off > 0; off >>= 1) {
        if (tid < off) sd[tid] += sd[tid + off];
        __syncthreads();
    }
    if (tid == 0) blockSums[blockIdx.x] = sd[0];
}

__global__ __launch_bounds__(128) void scan_b_kernel(int* blockSums, int nsb)
{
    __shared__ int sd[128];
    int tid = threadIdx.x;
    int v = (tid < nsb) ? blockSums[tid] : 0;
    sd[tid] = v; __syncthreads();
    for (int off = 1; off < 128; off <<= 1) {
        int a = (tid >= off) ? sd[tid - off] : 0;
        __syncthreads();
        sd[tid] += a;
        __syncthreads();
    }
    if (tid < nsb) blockSums[tid] = sd[tid] - v;   // exclusive
}

__global__ __launch_bounds__(256) void scan_c_kernel(
    const int* __restrict__ counts, const int* __restrict__ blockOffs,
    int* __restrict__ row_ptr, int* __restrict__ cursor)
{
    __shared__ int sc[256];
    int tid = threadIdx.x;
    int base = blockIdx.x * SCAN_BLK + tid * 4;
    int c[4]; int ts = 0;
#pragma unroll
    for (int k = 0; k < 4; ++k) {
        int i = base + k;
        c[k] = (i < N_NODES) ? counts[i] : 0;
        ts += c[k];
    }
    sc[tid] = ts; __syncthreads();
    for (int off = 1; off < 256; off <<= 1) {
        int a = (tid >= off) ? sc[tid - off] : 0;
        __syncthreads();
        sc[tid] += a;
        __syncthreads();
    }
    int run = blockOffs[blockIdx.x] + sc[tid] - ts;
#pragma unroll
    for (int k = 0; k < 4; ++k) {
        int i = base + k;
        if (i < N_NODES) { row_ptr[i] = run; cursor[i] = run; run += c[k]; }
    }
    if (blockIdx.x == 0 && tid == 0) row_ptr[N_NODES] = N_EDGES;
}

__global__ __launch_bounds__(256) void fill_kernel(
    const int* __restrict__ ei, int* __restrict__ cursor,
    int* __restrict__ edge_src)
{
    int e = blockIdx.x * 256 + threadIdx.x;
    if (e >= N_EDGES) return;
    int dst = ei[N_EDGES + e];
    int pos = atomicAdd(&cursor[dst], 1);
    edge_src[pos] = ei[e];
}

// ---------------- GEMM1: y = h @ W1 ----------------
template<int K>
__global__ __launch_bounds__(256) void gemm1_kernel(
    const float* __restrict__ h, const float* __restrict__ W,
    float* __restrict__ y, int n)
{
    __shared__ float Wl[K * DIM];
    for (int i = threadIdx.x; i < K * DIM; i += 256) Wl[i] = W[i];
    __syncthreads();

    int row = blockIdx.x * 256 + threadIdx.x;
    if (row >= n) return;

    float acc[DIM];
#pragma unroll
    for (int j = 0; j < DIM; ++j) acc[j] = 0.f;

    const float* hr = h + (long)row * K;
    for (int k = 0; k < K; ++k) {
        float xv = hr[k];
#pragma unroll
        for (int j = 0; j < DIM; ++j) acc[j] += xv * Wl[k * DIM + j];
    }

    float4* yv = (float4*)(y + (long)row * DIM);
#pragma unroll
    for (int q = 0; q < DIM / 4; ++q)
        yv[q] = make_float4(acc[q*4+0], acc[q*4+1], acc[q*4+2], acc[q*4+3]);
}

// ------- aggregate (CSR gather): s[i] = y[i] + b1 + sum_in y[src] -------
__global__ __launch_bounds__(256) void aggregate_kernel(
    const int* __restrict__ row_ptr, const int* __restrict__ edge_src,
    const float* __restrict__ y, const float* __restrict__ b,
    float* __restrict__ s)
{
    int t = blockIdx.x * 256 + threadIdx.x;
    if (t >= N_NODES * 8) return;
    int node = t >> 3;
    int p = t & 7;

    float4 acc = *(const float4*)(y + (long)node * DIM + p * 4);
    float4 bb = *(const float4*)(b + p * 4);
    acc.x += bb.x; acc.y += bb.y; acc.z += bb.z; acc.w += bb.w;

    int beg = row_ptr[node];
    int end = row_ptr[node + 1];
    for (int e = beg; e < end; ++e) {
        int src = edge_src[e];
        float4 v = *(const float4*)(y + (long)src * DIM + p * 4);
        acc.x += v.x; acc.y += v.y; acc.z += v.z; acc.w += v.w;
    }
    *(float4*)(s + (long)node * DIM + p * 4) = acc;
}

// ------- GEMM2: z = relu(relu(s) @ W2 + b2); per-block partial stats -------
__global__ __launch_bounds__(256) void gemm2_kernel(
    const float* __restrict__ s, const float* __restrict__ W2,
    const float* __restrict__ b2, float* __restrict__ z,
    float* __restrict__ partial, int n)
{
    __shared__ float Wl[DIM * DIM];
    __shared__ float bl[DIM];
    __shared__ float psum[4][DIM];
    __shared__ float psq[4][DIM];
    for (int i = threadIdx.x; i < DIM * DIM; i += 256) Wl[i] = W2[i];
    if (threadIdx.x < DIM) bl[threadIdx.x] = b2[threadIdx.x];
    __syncthreads();

    int row = blockIdx.x * 256 + threadIdx.x;
    float zv[DIM];
    if (row < n) {
        float a[DIM];
        const float4* sv = (const float4*)(s + (long)row * DIM);
#pragma unroll
        for (int q = 0; q < DIM / 4; ++q) {
            float4 v = sv[q];
            a[q*4+0] = fmaxf(v.x, 0.f);
            a[q*4+1] = fmaxf(v.y, 0.f);
            a[q*4+2] = fmaxf(v.z, 0.f);
            a[q*4+3] = fmaxf(v.w, 0.f);
        }
#pragma unroll
        for (int j = 0; j < DIM; ++j) zv[j] = bl[j];
#pragma unroll
        for (int k = 0; k < DIM; ++k) {
#pragma unroll
            for (int j = 0; j < DIM; ++j) zv[j] += a[k] * Wl[k * DIM + j];
        }
#pragma unroll
        for (int j = 0; j < DIM; ++j) zv[j] = fmaxf(zv[j], 0.f);
        float4* zp = (float4*)(z + (long)row * DIM);
#pragma unroll
        for (int q = 0; q < DIM / 4; ++q)
            zp[q] = make_float4(zv[q*4+0], zv[q*4+1], zv[q*4+2], zv[q*4+3]);
    } else {
#pragma unroll
        for (int j = 0; j < DIM; ++j) zv[j] = 0.f;
    }

    float sq[DIM];
#pragma unroll
    for (int j = 0; j < DIM; ++j) sq[j] = zv[j] * zv[j];
#pragma unroll
    for (int off = 1; off < 64; off <<= 1) {
#pragma unroll
        for (int j = 0; j < DIM; ++j) {
            zv[j] += __shfl_xor(zv[j], off, 64);
            sq[j] += __shfl_xor(sq[j], off, 64);
        }
    }
    int wid = threadIdx.x >> 6, lane = threadIdx.x & 63;
    if (lane == 0) {
#pragma unroll
        for (int j = 0; j < DIM; ++j) { psum[wid][j] = zv[j]; psq[wid][j] = sq[j]; }
    }
    __syncthreads();
    if (threadIdx.x < DIM) {
        int c = threadIdx.x;
        float a = psum[0][c] + psum[1][c] + psum[2][c] + psum[3][c];
        float q = psq[0][c] + psq[1][c] + psq[2][c] + psq[3][c];
        partial[(long)blockIdx.x * 2 * DIM + c] = a;
        partial[(long)blockIdx.x * 2 * DIM + DIM + c] = q;
    }
}

// ---------------- finalize stats -> scale/shift ----------------
__global__ __launch_bounds__(256) void finalize_kernel(
    const float* __restrict__ partial, int nparts,
    const float* __restrict__ gamma, const float* __restrict__ beta,
    float* __restrict__ ss)
{
    __shared__ float red[256];
    int t = threadIdx.x;
    int c = t & 63;        // 0..31 = sum, 32..63 = sumsq
    int chunk = t >> 6;    // 4 chunks
    float a = 0.f;
    for (int p = chunk; p < nparts; p += 4) a += partial[(long)p * 64 + c];
    red[t] = a; __syncthreads();
    if (t < 64) red[t] = red[t] + red[t+64] + red[t+128] + red[t+192];
    __syncthreads();
    if (t < DIM) {
        const float invN = 1.0f / (float)N_NODES;
        float S = red[t], Q = red[t + DIM];
        float mu = S * invN;
        float var = Q * invN - mu * mu;
        float scale = gamma[t] * rsqrtf(var + BN_EPS);
        ss[t] = scale;
        ss[DIM + t] = beta[t] - mu * scale;
    }
}

// ---------------- BN apply (in place on z) ----------------
__global__ __launch_bounds__(256) void bn_kernel(
    float* __restrict__ z, const float* __restrict__ ss)
{
    __shared__ float sc[DIM], sh[DIM];
    if (threadIdx.x < DIM) {
        sc[threadIdx.x] = ss[threadIdx.x];
        sh[threadIdx.x] = ss[DIM + threadIdx.x];
    }
    __syncthreads();
    int t = blockIdx.x * 256 + threadIdx.x;   // float4 index
    if (t >= N_NODES * (DIM / 4)) return;
    float4 v = ((float4*)z)[t];
    int c = (t & 7) * 4;
    v.x = v.x * sc[c + 0] + sh[c + 0];
    v.y = v.y * sc[c + 1] + sh[c + 1];
    v.z = v.z * sc[c + 2] + sh[c + 2];
    v.w = v.w * sc[c + 3] + sh[c + 3];
    ((float4*)z)[t] = v;
}

// ---------------- global add pool ----------------
__global__ __launch_bounds__(256) void pool_kernel(
    const float* __restrict__ z, const int* __restrict__ batch,
    float* __restrict__ pooled)
{
    int t = blockIdx.x * 256 + threadIdx.x;
    if (t >= N_NODES * 8) return;
    int nrow = t >> 3;
    int p = t & 7;
    int g = batch[nrow];
    float4 v = *(const float4*)(z + (long)nrow * DIM + p * 4);
    float* d = pooled + (long)g * DIM + p * 4;
    atomicAdd(d + 0, v.x);
    atomicAdd(d + 1, v.y);
    atomicAdd(d + 2, v.z);
    atomicAdd(d + 3, v.w);
}

// ---------------- final FC + ReLU ----------------
__global__ __launch_bounds__(256) void fc_kernel(
    const float* __restrict__ pooled, const float* __restrict__ Wfc,
    const float* __restrict__ bfc, float* __restrict__ out)
{
    __shared__ float Wl[DIM * OUTD];   // 16 KB
    for (int i = threadIdx.x; i < DIM * OUTD; i += 256) Wl[i] = Wfc[i];
    __syncthreads();
    int t = blockIdx.x * 256 + threadIdx.x;
    if (t >= N_GRAPHS * OUTD) return;
    int g = t >> 7;
    int o = t & (OUTD - 1);
    float acc = bfc[o];
    const float* pr = pooled + (long)g * DIM;
#pragma unroll
    for (int k = 0; k < DIM; ++k) acc += pr[k] * Wl[k * OUTD + o];
    out[t] = fmaxf(acc, 0.f);
}

extern "C" void kernel_launch(void* const* d_in, const int* in_sizes, int n_in,
                              void* d_out, int out_size, void* d_ws, size_t ws_size,
                              hipStream_t stream) {
    const float* x      = (const float*)d_in[0];
    const int*   ei     = (const int*)  d_in[1];
    const int*   batch  = (const int*)  d_in[2];
    const float* W1_0   = (const float*)d_in[3];
    const float* W1_rest= (const float*)d_in[4];
    const float* b1     = (const float*)d_in[5];
    const float* W2     = (const float*)d_in[6];
    const float* b2     = (const float*)d_in[7];
    const float* gamma  = (const float*)d_in[8];
    const float* beta   = (const float*)d_in[9];
    const float* Wfc    = (const float*)d_in[10];
    const float* bfc    = (const float*)d_in[11];
    float* out = (float*)d_out;

    char* ws = (char*)d_ws;
    const size_t nb = (size_t)N_NODES * DIM * sizeof(float);   // 12.8 MB
    float* y      = (float*)(ws);
    float* s      = (float*)(ws + nb);
    float* z      = (float*)(ws + 2 * nb);
    char*  p4     = ws + 3 * nb;
    float* pooled = (float*)p4;                                 // 256 KB
    float* ss     = pooled + (size_t)N_GRAPHS * DIM;            // 64 floats
    float* partial= ss + 2 * DIM;                               // 391*64 floats
    const int rowBlocks = (N_NODES + 255) / 256;                // 391
    int*   counts = (int*)(partial + (size_t)rowBlocks * 2 * DIM);
    int*   row_ptr= counts + N_NODES;
    int*   cursor = row_ptr + (N_NODES + 1);
    int*   blockSums = cursor + N_NODES;
    const int nsb = (N_NODES + SCAN_BLK - 1) / SCAN_BLK;        // 98
    int*   edge_src = blockSums + 128;

    // zero: pooled + counts
    hipMemsetAsync(pooled, 0, (size_t)N_GRAPHS * DIM * sizeof(float), stream);
    hipMemsetAsync(counts, 0, (size_t)N_NODES * sizeof(int), stream);

    const int edgeBlocks = (N_EDGES + 255) / 256;
    const int elemBlocks = (N_NODES * 8 + 255) / 256;

    // CSR build
    deg_kernel<<<edgeBlocks, 256, 0, stream>>>(ei, counts);
    scan_a_kernel<<<nsb, 256, 0, stream>>>(counts, blockSums);
    scan_b_kernel<<<1, 128, 0, stream>>>(blockSums, nsb);
    scan_c_kernel<<<nsb, 256, 0, stream>>>(counts, blockSums, row_ptr, cursor);
    fill_kernel<<<edgeBlocks, 256, 0, stream>>>(ei, cursor, edge_src);

    const float* hin = x;
    for (int i = 0; i < NLAYERS; ++i) {
        if (i == 0) {
            gemm1_kernel<NFEAT><<<rowBlocks, 256, 0, stream>>>(hin, W1_0, y, N_NODES);
        } else {
            gemm1_kernel<DIM><<<rowBlocks, 256, 0, stream>>>(
                hin, W1_rest + (size_t)(i - 1) * DIM * DIM, y, N_NODES);
        }
        aggregate_kernel<<<elemBlocks, 256, 0, stream>>>(
            row_ptr, edge_src, y, b1 + i * DIM, s);
        gemm2_kernel<<<rowBlocks, 256, 0, stream>>>(
            s, W2 + (size_t)i * DIM * DIM, b2 + i * DIM, z, partial, N_NODES);
        finalize_kernel<<<1, 256, 0, stream>>>(
            partial, rowBlocks, gamma + i * DIM, beta + i * DIM, ss);
        bn_kernel<<<elemBlocks, 256, 0, stream>>>(z, ss);
        hin = z;
    }

    pool_kernel<<<elemBlocks, 256, 0, stream>>>(z, batch, pooled);
    fc_kernel<<<(N_GRAPHS * OUTD) / 256, 256, 0, stream>>>(pooled, Wfc, bfc, out);
}

// Round 3
// 621.766 us; speedup vs baseline: 10.5388x; 1.3045x over previous
//
#include <hip/hip_runtime.h>

#define N_NODES 100000
#define N_EDGES 1600000
#define N_GRAPHS 2048
#define NFEAT 78
#define DIM 32
#define NLAYERS 5
#define OUTD 128
#define BN_EPS 1e-5f
#define SCAN_BLK 1024
#define NB 6250        // buckets = N_NODES/16
#define BCAP 512       // bucket capacity (mean 256, +16 sigma)

// ---------- bucket fill: bdata[b] <- src | (dst&15)<<20 ----------
__global__ __launch_bounds__(256) void bfill_kernel(
    const int* __restrict__ ei, int* __restrict__ bcnt, int* __restrict__ bdata)
{
    int e = blockIdx.x * 256 + threadIdx.x;
    if (e >= N_EDGES) return;
    int src = ei[e];
    int dst = ei[N_EDGES + e];
    int b = dst >> 4;
    int pos = atomicAdd(&bcnt[b], 1);
    if (pos < BCAP) bdata[b * BCAP + pos] = src | ((dst & 15) << 20);
}

// ---------- per-node counts via LDS (one block per bucket) ----------
__global__ __launch_bounds__(256) void pcount_kernel(
    const int* __restrict__ bcnt, const int* __restrict__ bdata,
    int* __restrict__ counts)
{
    __shared__ int cnt[16];
    int b = blockIdx.x;
    if (threadIdx.x < 16) cnt[threadIdx.x] = 0;
    __syncthreads();
    int n = bcnt[b]; n = n < BCAP ? n : BCAP;
    for (int e = threadIdx.x; e < n; e += 256)
        atomicAdd(&cnt[bdata[b * BCAP + e] >> 20], 1);
    __syncthreads();
    if (threadIdx.x < 16) counts[b * 16 + threadIdx.x] = cnt[threadIdx.x];
}

// ---------- hierarchical exclusive scan over counts (100K) ----------
__global__ __launch_bounds__(256) void scan_a_kernel(
    const int* __restrict__ counts, int* __restrict__ blockSums)
{
    __shared__ int sd[256];
    int tid = threadIdx.x;
    int base = blockIdx.x * SCAN_BLK + tid * 4;
    int s = 0;
#pragma unroll
    for (int k = 0; k < 4; ++k) {
        int i = base + k;
        if (i < N_NODES) s += counts[i];
    }
    sd[tid] = s; __syncthreads();
    for (int off = 128; off > 0; off >>= 1) {
        if (tid < off) sd[tid] += sd[tid + off];
        __syncthreads();
    }
    if (tid == 0) blockSums[blockIdx.x] = sd[0];
}

__global__ __launch_bounds__(128) void scan_b_kernel(int* blockSums, int nsb)
{
    __shared__ int sd[128];
    int tid = threadIdx.x;
    int v = (tid < nsb) ? blockSums[tid] : 0;
    sd[tid] = v; __syncthreads();
    for (int off = 1; off < 128; off <<= 1) {
        int a = (tid >= off) ? sd[tid - off] : 0;
        __syncthreads();
        sd[tid] += a;
        __syncthreads();
    }
    if (tid < nsb) blockSums[tid] = sd[tid] - v;   // exclusive
}

__global__ __launch_bounds__(256) void scan_c_kernel(
    const int* __restrict__ counts, const int* __restrict__ blockOffs,
    int* __restrict__ row_ptr)
{
    __shared__ int sc[256];
    int tid = threadIdx.x;
    int base = blockIdx.x * SCAN_BLK + tid * 4;
    int c[4]; int ts = 0;
#pragma unroll
    for (int k = 0; k < 4; ++k) {
        int i = base + k;
        c[k] = (i < N_NODES) ? counts[i] : 0;
        ts += c[k];
    }
    sc[tid] = ts; __syncthreads();
    for (int off = 1; off < 256; off <<= 1) {
        int a = (tid >= off) ? sc[tid - off] : 0;
        __syncthreads();
        sc[tid] += a;
        __syncthreads();
    }
    int run = blockOffs[blockIdx.x] + sc[tid] - ts;
#pragma unroll
    for (int k = 0; k < 4; ++k) {
        int i = base + k;
        if (i < N_NODES) { row_ptr[i] = run; run += c[k]; }
    }
    if (blockIdx.x == 0 && tid == 0) row_ptr[N_NODES] = N_EDGES;
}

// ---------- final CSR fill via LDS cursors (one block per bucket) ----------
__global__ __launch_bounds__(256) void cfill_kernel(
    const int* __restrict__ bcnt, const int* __restrict__ bdata,
    const int* __restrict__ row_ptr, int* __restrict__ edge_src)
{
    __shared__ int cur[16];
    int b = blockIdx.x;
    if (threadIdx.x < 16) cur[threadIdx.x] = row_ptr[b * 16 + threadIdx.x];
    __syncthreads();
    int n = bcnt[b]; n = n < BCAP ? n : BCAP;
    for (int e = threadIdx.x; e < n; e += 256) {
        int d = bdata[b * BCAP + e];
        int pos = atomicAdd(&cur[d >> 20], 1);
        edge_src[pos] = d & 0xFFFFF;
    }
}

// ---------- GEMM1 (8 threads/row): y = affine(h) @ W1 ----------
template<int K, bool AFF>
__global__ __launch_bounds__(256) void gemm1f_kernel(
    const float* __restrict__ h, const float* __restrict__ W,
    const float* __restrict__ ss, float* __restrict__ y)
{
    __shared__ float Wl[K * DIM];
    __shared__ float scl[DIM], shl[DIM];
    for (int i = threadIdx.x; i < K * DIM; i += 256) Wl[i] = W[i];
    if (AFF && threadIdx.x < DIM) {
        scl[threadIdx.x] = ss[threadIdx.x];
        shl[threadIdx.x] = ss[DIM + threadIdx.x];
    }
    __syncthreads();

    int t = blockIdx.x * 256 + threadIdx.x;
    int row = t >> 3;
    int c0 = (t & 7) * 4;

    float4 acc = make_float4(0.f, 0.f, 0.f, 0.f);
    const float* hr = h + (long)row * K;
    for (int k = 0; k < K; ++k) {
        float xv = hr[k];
        if (AFF) xv = fmaf(xv, scl[k], shl[k]);
        acc.x += xv * Wl[k * DIM + c0 + 0];
        acc.y += xv * Wl[k * DIM + c0 + 1];
        acc.z += xv * Wl[k * DIM + c0 + 2];
        acc.w += xv * Wl[k * DIM + c0 + 3];
    }
    *(float4*)(y + (long)row * DIM + c0) = acc;
}

// ------- aggregate (CSR gather): s[i] = y[i] + b1 + sum_in y[src] -------
__global__ __launch_bounds__(256) void aggregate_kernel(
    const int* __restrict__ row_ptr, const int* __restrict__ edge_src,
    const float* __restrict__ y, const float* __restrict__ b,
    float* __restrict__ s)
{
    int t = blockIdx.x * 256 + threadIdx.x;
    int node = t >> 3;
    int p = t & 7;

    float4 acc = *(const float4*)(y + (long)node * DIM + p * 4);
    float4 bb = *(const float4*)(b + p * 4);
    acc.x += bb.x; acc.y += bb.y; acc.z += bb.z; acc.w += bb.w;

    int beg = row_ptr[node];
    int end = row_ptr[node + 1];
    for (int e = beg; e < end; ++e) {
        int src = edge_src[e];
        float4 v = *(const float4*)(y + (long)src * DIM + p * 4);
        acc.x += v.x; acc.y += v.y; acc.z += v.z; acc.w += v.w;
    }
    *(float4*)(s + (long)node * DIM + p * 4) = acc;
}

// ------- GEMM2: z = relu(relu(s) @ W2 + b2); per-block partial stats -------
__global__ __launch_bounds__(256) void gemm2_kernel(
    const float* __restrict__ s, const float* __restrict__ W2,
    const float* __restrict__ b2, float* __restrict__ z,
    float* __restrict__ partial, int n)
{
    __shared__ float Wl[DIM * DIM];
    __shared__ float bl[DIM];
    __shared__ float psum[4][DIM];
    __shared__ float psq[4][DIM];
    for (int i = threadIdx.x; i < DIM * DIM; i += 256) Wl[i] = W2[i];
    if (threadIdx.x < DIM) bl[threadIdx.x] = b2[threadIdx.x];
    __syncthreads();

    int row = blockIdx.x * 256 + threadIdx.x;
    float zv[DIM];
    if (row < n) {
        float a[DIM];
        const float4* sv = (const float4*)(s + (long)row * DIM);
#pragma unroll
        for (int q = 0; q < DIM / 4; ++q) {
            float4 v = sv[q];
            a[q*4+0] = fmaxf(v.x, 0.f);
            a[q*4+1] = fmaxf(v.y, 0.f);
            a[q*4+2] = fmaxf(v.z, 0.f);
            a[q*4+3] = fmaxf(v.w, 0.f);
        }
#pragma unroll
        for (int j = 0; j < DIM; ++j) zv[j] = bl[j];
#pragma unroll
        for (int k = 0; k < DIM; ++k) {
#pragma unroll
            for (int j = 0; j < DIM; ++j) zv[j] += a[k] * Wl[k * DIM + j];
        }
#pragma unroll
        for (int j = 0; j < DIM; ++j) zv[j] = fmaxf(zv[j], 0.f);
        float4* zp = (float4*)(z + (long)row * DIM);
#pragma unroll
        for (int q = 0; q < DIM / 4; ++q)
            zp[q] = make_float4(zv[q*4+0], zv[q*4+1], zv[q*4+2], zv[q*4+3]);
    } else {
#pragma unroll
        for (int j = 0; j < DIM; ++j) zv[j] = 0.f;
    }

    float sq[DIM];
#pragma unroll
    for (int j = 0; j < DIM; ++j) sq[j] = zv[j] * zv[j];
#pragma unroll
    for (int off = 1; off < 64; off <<= 1) {
#pragma unroll
        for (int j = 0; j < DIM; ++j) {
            zv[j] += __shfl_xor(zv[j], off, 64);
            sq[j] += __shfl_xor(sq[j], off, 64);
        }
    }
    int wid = threadIdx.x >> 6, lane = threadIdx.x & 63;
    if (lane == 0) {
#pragma unroll
        for (int j = 0; j < DIM; ++j) { psum[wid][j] = zv[j]; psq[wid][j] = sq[j]; }
    }
    __syncthreads();
    if (threadIdx.x < DIM) {
        int c = threadIdx.x;
        float a = psum[0][c] + psum[1][c] + psum[2][c] + psum[3][c];
        float q = psq[0][c] + psq[1][c] + psq[2][c] + psq[3][c];
        partial[(long)blockIdx.x * 2 * DIM + c] = a;
        partial[(long)blockIdx.x * 2 * DIM + DIM + c] = q;
    }
}

// ---------------- finalize stats -> scale/shift ----------------
__global__ __launch_bounds__(256) void finalize_kernel(
    const float* __restrict__ partial, int nparts,
    const float* __restrict__ gamma, const float* __restrict__ beta,
    float* __restrict__ ss)
{
    __shared__ float red[256];
    int t = threadIdx.x;
    int c = t & 63;
    int chunk = t >> 6;
    float a = 0.f;
    for (int p = chunk; p < nparts; p += 4) a += partial[(long)p * 64 + c];
    red[t] = a; __syncthreads();
    if (t < 64) red[t] = red[t] + red[t+64] + red[t+128] + red[t+192];
    __syncthreads();
    if (t < DIM) {
        const float invN = 1.0f / (float)N_NODES;
        float S = red[t], Q = red[t + DIM];
        float mu = S * invN;
        float var = Q * invN - mu * mu;
        float scale = gamma[t] * rsqrtf(var + BN_EPS);
        ss[t] = scale;
        ss[DIM + t] = beta[t] - mu * scale;
    }
}

// ------- pool: pooled[g] += affine(z[node]); sorted-batch LDS dedup -------
__global__ __launch_bounds__(256) void pool_kernel(
    const float* __restrict__ z, const int* __restrict__ batch,
    const float* __restrict__ ss, float* __restrict__ pooled)
{
    __shared__ float acc[32][32];
    __shared__ int slot[32];
    __shared__ int segg[32];
    __shared__ int nsegS;
    __shared__ float scl[DIM], shl[DIM];
    int tid = threadIdx.x;
    for (int i = tid; i < 1024; i += 256) ((float*)acc)[i] = 0.f;
    if (tid < DIM) { scl[tid] = ss[tid]; shl[tid] = ss[DIM + tid]; }
    int nodeBase = blockIdx.x * 32;
    if (tid < 32) {
        int nd = nodeBase + tid;
        int gv = batch[nd];
        int flag = (tid == 0) ? 1 : (gv != batch[nd - 1]);
        unsigned long long m = __ballot(flag);
        int s = __popcll(m & ((2ull << tid) - 1ull)) - 1;
        slot[tid] = s;
        if (flag) segg[s] = gv;
        if (tid == 0) nsegS = __popcll(m);
    }
    __syncthreads();

    int ln = tid >> 3;          // local node 0..31
    int p = tid & 7;
    int node = nodeBase + ln;
    float4 v = *(const float4*)(z + (long)node * DIM + p * 4);
    int c = p * 4;
    v.x = fmaf(v.x, scl[c+0], shl[c+0]);
    v.y = fmaf(v.y, scl[c+1], shl[c+1]);
    v.z = fmaf(v.z, scl[c+2], shl[c+2]);
    v.w = fmaf(v.w, scl[c+3], shl[c+3]);
    int s = slot[ln];
    atomicAdd(&acc[s][c+0], v.x);
    atomicAdd(&acc[s][c+1], v.y);
    atomicAdd(&acc[s][c+2], v.z);
    atomicAdd(&acc[s][c+3], v.w);
    __syncthreads();

    int total = nsegS * 32;
    for (int i = tid; i < total; i += 256) {
        int r = i >> 5, d = i & 31;
        float val = acc[r][d];
        if (val != 0.f) atomicAdd(&pooled[(long)segg[r] * DIM + d], val);
    }
}

// ---------------- final FC + ReLU ----------------
__global__ __launch_bounds__(256) void fc_kernel(
    const float* __restrict__ pooled, const float* __restrict__ Wfc,
    const float* __restrict__ bfc, float* __restrict__ out)
{
    __shared__ float Wl[DIM * OUTD];   // 16 KB
    for (int i = threadIdx.x; i < DIM * OUTD; i += 256) Wl[i] = Wfc[i];
    __syncthreads();
    int t = blockIdx.x * 256 + threadIdx.x;
    if (t >= N_GRAPHS * OUTD) return;
    int g = t >> 7;
    int o = t & (OUTD - 1);
    float acc = bfc[o];
    const float* pr = pooled + (long)g * DIM;
#pragma unroll
    for (int k = 0; k < DIM; ++k) acc += pr[k] * Wl[k * OUTD + o];
    out[t] = fmaxf(acc, 0.f);
}

extern "C" void kernel_launch(void* const* d_in, const int* in_sizes, int n_in,
                              void* d_out, int out_size, void* d_ws, size_t ws_size,
                              hipStream_t stream) {
    const float* x      = (const float*)d_in[0];
    const int*   ei     = (const int*)  d_in[1];
    const int*   batch  = (const int*)  d_in[2];
    const float* W1_0   = (const float*)d_in[3];
    const float* W1_rest= (const float*)d_in[4];
    const float* b1     = (const float*)d_in[5];
    const float* W2     = (const float*)d_in[6];
    const float* b2     = (const float*)d_in[7];
    const float* gamma  = (const float*)d_in[8];
    const float* beta   = (const float*)d_in[9];
    const float* Wfc    = (const float*)d_in[10];
    const float* bfc    = (const float*)d_in[11];
    float* out = (float*)d_out;

    char* ws = (char*)d_ws;
    const size_t nf = (size_t)N_NODES * DIM;                   // 3.2M floats
    float* y      = (float*)ws;
    float* s      = y + nf;
    float* z      = s + nf;          // overlaid with bdata (both 3.2M words)
    int*   bdata  = (int*)z;         // NB*BCAP = 3,200,000 ints exactly
    float* pooled = z + nf;                                    // 65536
    float* ss     = pooled + (size_t)N_GRAPHS * DIM;           // 5*64
    float* partial= ss + NLAYERS * 2 * DIM;                    // 391*64
    const int rowBlocks = (N_NODES + 255) / 256;               // 391
    int*   counts = (int*)(partial + (size_t)rowBlocks * 2 * DIM);
    int*   row_ptr= counts + N_NODES;                          // 100001
    int*   blockSums = row_ptr + (N_NODES + 1);                // 128
    int*   bcnt   = blockSums + 128;                           // 6250
    int*   edge_src = bcnt + NB;                               // 1.6M

    hipMemsetAsync(pooled, 0, (size_t)N_GRAPHS * DIM * sizeof(float), stream);
    hipMemsetAsync(bcnt, 0, (size_t)NB * sizeof(int), stream);

    const int edgeBlocks = (N_EDGES + 255) / 256;
    const int grpBlocks = (N_NODES * 8) / 256;                 // 3125
    const int nsb = (N_NODES + SCAN_BLK - 1) / SCAN_BLK;       // 98

    // CSR build (bucketed)
    bfill_kernel<<<edgeBlocks, 256, 0, stream>>>(ei, bcnt, bdata);
    pcount_kernel<<<NB, 256, 0, stream>>>(bcnt, bdata, counts);
    scan_a_kernel<<<nsb, 256, 0, stream>>>(counts, blockSums);
    scan_b_kernel<<<1, 128, 0, stream>>>(blockSums, nsb);
    scan_c_kernel<<<nsb, 256, 0, stream>>>(counts, blockSums, row_ptr);
    cfill_kernel<<<NB, 256, 0, stream>>>(bcnt, bdata, row_ptr, edge_src);

    const float* hin = x;
    for (int i = 0; i < NLAYERS; ++i) {
        if (i == 0) {
            gemm1f_kernel<NFEAT, false><<<grpBlocks, 256, 0, stream>>>(
                hin, W1_0, nullptr, y);
        } else {
            gemm1f_kernel<DIM, true><<<grpBlocks, 256, 0, stream>>>(
                hin, W1_rest + (size_t)(i - 1) * DIM * DIM,
                ss + (i - 1) * 2 * DIM, y);
        }
        aggregate_kernel<<<grpBlocks, 256, 0, stream>>>(
            row_ptr, edge_src, y, b1 + i * DIM, s);
        gemm2_kernel<<<rowBlocks, 256, 0, stream>>>(
            s, W2 + (size_t)i * DIM * DIM, b2 + i * DIM, z, partial, N_NODES);
        finalize_kernel<<<1, 256, 0, stream>>>(
            partial, rowBlocks, gamma + i * DIM, beta + i * DIM,
            ss + i * 2 * DIM);
        hin = z;
    }

    pool_kernel<<<N_NODES / 32, 256, 0, stream>>>(
        z, batch, ss + (NLAYERS - 1) * 2 * DIM, pooled);
    fc_kernel<<<(N_GRAPHS * OUTD) / 256, 256, 0, stream>>>(pooled, Wfc, bfc, out);
}